// Round 1
// baseline (81.312 us; speedup 1.0000x reference)
//
#include <hip/hip_runtime.h>

// Problem constants (from reference setup_inputs)
constexpr int cB = 32, cC = 6, cT = 64;
constexpr int cK = 8, cN = 128;
constexpr int cS = 32, cP = 64;
constexpr int NSEG_PAD = cK * cN;     // 1024 float2 slots; n==127 are pads
constexpr int NCL  = cS * cP;         // 2048 centerline points per batch
constexpr int G = 4;                  // blocks per (b,c); 16 points per block
constexpr int PPW = 4;                // points per wave (register-blocked)
constexpr int NWAVES = 8;             // 4 point-groups x 2 slot-halves
constexpr int NIT_H = (NSEG_PAD / 2) / 64;   // 8 iterations per half
constexpr float F_EPS = 1e-6f;
constexpr float F_THRESHOLD = 0.5f;

// 768 blocks x 512 threads (8 waves). Waves (pw, h): pw = point group
// (4 consecutive t's), h = which half of the slot space this wave scans.
// vs the 82us version: same inner-loop code, but each wave does HALF the
// trip count (8 iters/pass) and the block carries 2x the waves -> demanded
// occupancy 3 -> 6 waves/SIMD, halved per-wave serial latency chains.
// Halves are combined via LDS: argmin by lexicographic (d2, idx) [bit-
// identical to global first-index argmin], min_d2 by fmin, hit by OR.
__global__ __launch_bounds__(512, 4) void offroad_kernel(
    const float* __restrict__ points,         // (B, C, T, 2)
    const float* __restrict__ road_boundary,  // (B, K, N, 2)
    const float* __restrict__ centerlines,    // (B, S, P, 2)
    float* __restrict__ out)                  // (B, C), pre-zeroed
{
    const int blk  = blockIdx.x;         // 0 .. B*C*G-1
    const int g    = blk & (G - 1);
    const int bc   = blk >> 2;           // b*C + c
    const int b    = bc / cC;
    const int lane = threadIdx.x & 63;
    const int wave = threadIdx.x >> 6;   // 0..7
    const int pw   = wave & 3;           // point group within block
    const int h    = wave >> 2;          // slot half (0 or 1)

    const float2* __restrict__ rb2 =
        (const float2*)(road_boundary + (size_t)b * cK * cN * 2);
    const float4* __restrict__ cl4 =
        (const float4*)(centerlines + (size_t)b * NCL * 2);

    // 4 consecutive points for this wave (wave-uniform -> broadcast loads)
    const int t0 = (g << 4) | (pw << 2);   // in [0, 64)
    const float* pb = points + (((size_t)bc) * cT + t0) * 2;
    float px[PPW], py[PPW];
    #pragma unroll
    for (int p = 0; p < PPW; ++p) { px[p] = pb[2 * p]; py[p] = pb[2 * p + 1]; }

    // Hoist pass-2's first segment load: its ~200cy L2 latency hides under
    // the entirety of pass 1 (the pre-barrier vmcnt drain lands long after).
    const int s2base = (h << 9) | lane;      // first rb2 slot for this wave
    const float2 a_init = rb2[s2base];

    // ---- Pass 1: centerline argmin (first-index tie-break), half range ----
    float best_d2[PPW];
    int   best_i[PPW];
    #pragma unroll
    for (int p = 0; p < PPW; ++p) { best_d2[p] = 3.4e38f; best_i[p] = 0x7fffffff; }

    {
        int s = (h << 9) | lane;             // float4 slot in [h*512, h*512+512)
        float4 cp = cl4[s];
        #pragma unroll 4
        for (int i = 0; i < NIT_H; ++i) {
            const float4 cpc = cp;
            const int sc = s;
            s += 64;
            if (i < NIT_H - 1) cp = cl4[s];    // prefetch (loop-carried)
            const int ia = 2 * sc;
            #pragma unroll
            for (int p = 0; p < PPW; ++p) {
                float dxa = px[p] - cpc.x, dya = py[p] - cpc.y;
                float d2a = dxa * dxa + dya * dya;
                float dxb = px[p] - cpc.z, dyb = py[p] - cpc.w;
                float d2b = dxb * dxb + dyb * dyb;
                float dmin = d2a; int imin = ia;
                if (d2b < d2a) { dmin = d2b; imin = ia + 1; }  // lower idx on tie
                if (dmin < best_d2[p] ||
                    (dmin == best_d2[p] && imin < best_i[p])) {
                    best_d2[p] = dmin; best_i[p] = imin;
                }
            }
        }
    }
    // argmin butterfly across 64 lanes (tie -> lower index)
    #pragma unroll
    for (int off = 1; off <= 32; off <<= 1) {
        #pragma unroll
        for (int p = 0; p < PPW; ++p) {
            float od2 = __shfl_xor(best_d2[p], off);
            int   oi  = __shfl_xor(best_i[p], off);
            if (od2 < best_d2[p] || (od2 == best_d2[p] && oi < best_i[p])) {
                best_d2[p] = od2; best_i[p] = oi;
            }
        }
    }
    // cross-half argmin combine (lexicographic -> identical to global argmin)
    __shared__ float s_bd2[NWAVES][PPW];
    __shared__ int   s_bi [NWAVES][PPW];
    if (lane == 0) {
        #pragma unroll
        for (int p = 0; p < PPW; ++p) { s_bd2[wave][p] = best_d2[p]; s_bi[wave][p] = best_i[p]; }
    }
    __syncthreads();
    #pragma unroll
    for (int p = 0; p < PPW; ++p) {
        float od2 = s_bd2[wave ^ 4][p];      // partner wave, same point group
        int   oi  = s_bi [wave ^ 4][p];
        if (od2 < best_d2[p] || (od2 == best_d2[p] && oi < best_i[p])) {
            best_d2[p] = od2; best_i[p] = oi;
        }
    }

    // closest centerline point per point (wave-uniform broadcast loads)
    const float2* __restrict__ cl2 = (const float2*)cl4;
    float dax[PPW], day[PPW];
    #pragma unroll
    for (int p = 0; p < PPW; ++p) {
        float2 cc = cl2[best_i[p]];
        dax[p] = cc.x - px[p]; day[p] = cc.y - py[p];   // da = a2 - a1
    }

    // ---- Pass 2: fused segment distance + intersection, half range ----
    // Slot halves split at k-row boundaries (512 = 4 full k-rows), so the
    // lane-63 neighbor logic never crosses halves. Local i parity == global
    // parity (h*8 is even), so the pad detection is unchanged.
    float min_d2[PPW];
    int   hit[PPW];
    #pragma unroll
    for (int p = 0; p < PPW; ++p) { min_d2[p] = 3.4e38f; hit[p] = 0; }

    {
        int s = s2base;
        float2 a = a_init;
        #pragma unroll 2
        for (int i = 0; i < NIT_H; ++i) {
            const float2 ac = a;
            s += 64;
            float2 an = ac;                  // epilogue dummy (last i is odd ->
            if (i < NIT_H - 1) an = rb2[s];  // lane-63 slot is a pad, unused)

            // ALL lanes execute every shuffle (wave-uniform), then select:
            //   lanes 0..62: neighbor = lane+1's a
            //   lane 63, i even: next iteration's lane-0 a
            //   lane 63, i odd : pad slot (slot & 127 == 127) -> nx = a (d=0)
            float sd_x = __shfl_down(ac.x, 1);
            float sd_y = __shfl_down(ac.y, 1);
            float b0x  = __shfl(an.x, 0);
            float b0y  = __shfl(an.y, 0);
            const bool last = (lane == 63);
            const bool odd  = (i & 1) != 0;
            float nx_x = last ? (odd ? ac.x : b0x) : sd_x;
            float nx_y = last ? (odd ? ac.y : b0y) : sd_y;
            const int valid = (last && odd) ? 0 : 1;

            a = an;   // carry the prefetch forward

            const float dx = nx_x - ac.x, dy = nx_y - ac.y;
            const float inv_e2 =
                __builtin_amdgcn_rcpf(dx * dx + dy * dy + F_EPS);

            #pragma unroll
            for (int p = 0; p < PPW; ++p) {
                // shared: v1 = p - a  (== reference's dp = a1 - b1)
                float v1x = px[p] - ac.x, v1y = py[p] - ac.y;
                // point-to-segment distance (pad: d=0 -> endpoint distance,
                // >= adjacent real segment's distance -> min unaffected)
                float proj = (v1x * dx + v1y * dy) * inv_e2;
                proj = __builtin_amdgcn_fmed3f(proj, 0.0f, 1.0f);
                float ex = v1x - dx * proj;
                float ey = v1y - dy * proj;
                min_d2[p] = fminf(min_d2[p], ex * ex + ey * ey);
                // intersection, division-free (w = cross(da,db)+EPS):
                //   t,u in [0,1]  <=>  ct*w in [0,w^2] and cu*w in [0,w^2]
                float w  = dax[p] * dy - day[p] * dx + F_EPS;
                float w2 = w * w;
                float ct = (dax[p] * v1y - day[p] * v1x) * w;
                float cu = (dx * v1y - dy * v1x) * w;
                bool inb = (ct >= 0.0f) & (ct <= w2) & (cu >= 0.0f) & (cu <= w2);
                hit[p] |= valid & (int)inb;
            }
        }
    }

    // ---- reduce min_d2 / hit across 64 lanes ----
    #pragma unroll
    for (int off = 1; off <= 32; off <<= 1) {
        #pragma unroll
        for (int p = 0; p < PPW; ++p) {
            min_d2[p] = fminf(min_d2[p], __shfl_xor(min_d2[p], off));
            hit[p]   |= __shfl_xor(hit[p], off);
        }
    }

    // ---- cross-half combine + final loss, one atomic per point group ----
    __shared__ float s_md[4][PPW];
    __shared__ int   s_ht[4][PPW];
    if (h == 1 && lane == 0) {
        #pragma unroll
        for (int p = 0; p < PPW; ++p) { s_md[pw][p] = min_d2[p]; s_ht[pw][p] = hit[p]; }
    }
    __syncthreads();
    if (h == 0 && lane == 0) {
        float total = 0.0f;
        #pragma unroll
        for (int p = 0; p < PPW; ++p) {
            float m2 = fminf(min_d2[p], s_md[pw][p]);
            int   hh = hit[p] | s_ht[pw][p];
            float md = sqrtf(m2);
            float sd = hh ? md : -md;               // inside -> negative
            total += fmaxf(sd + F_THRESHOLD, 0.0f);
        }
        atomicAdd(&out[bc], total);
    }
}

extern "C" void kernel_launch(void* const* d_in, const int* in_sizes, int n_in,
                              void* d_out, int out_size, void* d_ws, size_t ws_size,
                              hipStream_t stream) {
    const float* points      = (const float*)d_in[0];
    const float* boundary    = (const float*)d_in[1];
    const float* centerlines = (const float*)d_in[2];
    float* out = (float*)d_out;
    hipMemsetAsync(out, 0, (size_t)out_size * sizeof(float), stream);
    offroad_kernel<<<cB * cC * G, 512, 0, stream>>>(points, boundary, centerlines, out);
}